// Round 4
// baseline (2102.787 us; speedup 1.0000x reference)
//
#include <hip/hip_runtime.h>

// GRNN scan: B=512 independent sequences, T=8192 steps.
// Round 3: producer/consumer split.
//  - Producer (1 lane): the cov/xi recurrence is batch-INDEPENDENT, so run it
//    once. P stays symmetric (P0=I, D=1e-3*I symmetric, AP+PA^T and XiXi^T
//    symmetric) -> track (p00,p01,p11) only. Store Xi[t] (float4) to d_ws.
//  - Consumer (512 blocks x 1 active lane = 2 waves/CU): x-recurrence per
//    batch, recomputing M = A - Xi C off the critical chain. Depth-1 register
//    software pipeline (8-step stages, ping-pong) hides L2/HBM latency.
// Fallback to the round-2 monolithic kernel if ws_size < 128 KB.

#define DT_C 1e-3f
#define MAXU 0.1f
#define T_LEN 8192
#define WS_BYTES (T_LEN * 4 * sizeof(float))   // xi[4] per step = 128 KB

__device__ __forceinline__ float clipf(float v, float lo, float hi) {
    return fminf(fmaxf(v, lo), hi);
}

// ---------------- producer: batch-invariant cov/xi recurrence ----------------
__global__ __launch_bounds__(64) void grnn_producer(
    const float* __restrict__ Am, const float* __restrict__ Cm,
    const float* __restrict__ Dm, float* __restrict__ ws)
{
    if (threadIdx.x != 0) return;
    const float a00 = Am[0], a01 = Am[1], a10 = Am[2], a11 = Am[3];
    const float c00 = Cm[0], c01 = Cm[1], c10 = Cm[2], c11 = Cm[3];
    const float d00 = Dm[0], d01 = Dm[1], d10 = Dm[2], d11 = Dm[3];

    float p00 = 1.f, p01 = 0.f, p11 = 1.f;   // symmetric P
    float4* __restrict__ w = reinterpret_cast<float4*>(ws);

#pragma unroll 8
    for (int t = 0; t < T_LEN; ++t) {
        // Xi = P C^T + D^T  (P symmetric: row0=(p00,p01), row1=(p01,p11))
        const float xi00 = fmaf(p00, c00, fmaf(p01, c01, d00));
        const float xi01 = fmaf(p00, c10, fmaf(p01, c11, d10));
        const float xi10 = fmaf(p01, c00, fmaf(p11, c01, d01));
        const float xi11 = fmaf(p01, c10, fmaf(p11, c11, d11));
        w[t] = make_float4(xi00, xi01, xi10, xi11);

        // U = A P   (P symmetric)
        const float u00 = fmaf(a00, p00, a01 * p01);
        const float u01 = fmaf(a00, p01, a01 * p11);
        const float u10 = fmaf(a10, p00, a11 * p01);
        const float u11 = fmaf(a10, p01, a11 * p11);

        // G = U + U^T + D - Xi Xi^T  (symmetric)
        const float g00 = fmaf(2.0f, u00, d00) - fmaf(xi00, xi00, xi01 * xi01);
        const float g01 = (u01 + u10 + d01)    - fmaf(xi00, xi10, xi01 * xi11);
        const float g11 = fmaf(2.0f, u11, d11) - fmaf(xi10, xi10, xi11 * xi11);

        p00 = clipf(fmaf(g00, DT_C, p00), -1.f, 1.f);
        p01 = clipf(fmaf(g01, DT_C, p01), -1.f, 1.f);
        p11 = clipf(fmaf(g11, DT_C, p11), -1.f, 1.f);
    }
}

// ---------------- consumer: per-batch x recurrence ----------------
__global__ __launch_bounds__(64) void grnn_consumer(
    const float* __restrict__ inp, const float* __restrict__ Am,
    const float* __restrict__ Cm, const float* __restrict__ ws,
    float* __restrict__ out)
{
    if (threadIdx.x != 0) return;
    const int b = blockIdx.x;

    const float a00 = Am[0], a01 = Am[1], a10 = Am[2], a11 = Am[3];
    const float c00 = Cm[0], c01 = Cm[1], c10 = Cm[2], c11 = Cm[3];
    const float c00dt = c00 * DT_C, c01dt = c01 * DT_C;
    const float c10dt = c10 * DT_C, c11dt = c11 * DT_C;

    const float4* __restrict__ in4 =
        reinterpret_cast<const float4*>(inp) + (size_t)b * (T_LEN / 2);
    float4* __restrict__ out4 =
        reinterpret_cast<float4*>(out) + (size_t)b * (T_LEN / 2);
    const float4* __restrict__ w = reinterpret_cast<const float4*>(ws);

    float x0 = 1.f, x1 = 0.f;

    constexpr int UN = 8;                 // steps per pipeline stage
    constexpr int NBLK = T_LEN / UN;      // 1024 stages (even)

    float4 dyA[UN / 2], xiA[UN];          // ping
    float4 dyB[UN / 2], xiB[UN];          // pong

#pragma unroll
    for (int i = 0; i < UN / 2; ++i) dyA[i] = in4[i];
#pragma unroll
    for (int i = 0; i < UN; ++i) xiA[i] = w[i];

    // one pipeline stage: compute UN steps from dy[]/xi[], write outputs
#define GRNN_STAGE(DY, XI, BLK)                                               \
    {                                                                         \
        _Pragma("unroll")                                                     \
        for (int s = 0; s < UN; s += 2) {                                     \
            const float4 d2 = (DY)[s / 2];                                    \
            float4 ov;                                                        \
            {   /* step s (uses d2.x, d2.y) */                                \
                const float4 xv = (XI)[s];                                    \
                const float m00 = a00 - fmaf(xv.x, c00, xv.y * c10);          \
                const float m01 = a01 - fmaf(xv.x, c01, xv.y * c11);          \
                const float m10 = a10 - fmaf(xv.z, c00, xv.w * c10);          \
                const float m11 = a11 - fmaf(xv.z, c01, xv.w * c11);          \
                ov.x = fmaf(c00dt, x0, c01dt * x1);                           \
                ov.y = fmaf(c10dt, x0, c11dt * x1);                           \
                const float t0 = fmaf(m00, x0, m01 * x1);                     \
                const float e0 = fmaf(xv.x, d2.x, xv.y * d2.y);               \
                const float t1 = fmaf(m10, x0, m11 * x1);                     \
                const float e1 = fmaf(xv.z, d2.x, xv.w * d2.y);               \
                x0 += clipf(fmaf(t0, DT_C, e0), -MAXU, MAXU);                 \
                x1 += clipf(fmaf(t1, DT_C, e1), -MAXU, MAXU);                 \
            }                                                                 \
            {   /* step s+1 (uses d2.z, d2.w) */                              \
                const float4 xv = (XI)[s + 1];                                \
                const float m00 = a00 - fmaf(xv.x, c00, xv.y * c10);          \
                const float m01 = a01 - fmaf(xv.x, c01, xv.y * c11);          \
                const float m10 = a10 - fmaf(xv.z, c00, xv.w * c10);          \
                const float m11 = a11 - fmaf(xv.z, c01, xv.w * c11);          \
                ov.z = fmaf(c00dt, x0, c01dt * x1);                           \
                ov.w = fmaf(c10dt, x0, c11dt * x1);                           \
                const float t0 = fmaf(m00, x0, m01 * x1);                     \
                const float e0 = fmaf(xv.x, d2.z, xv.y * d2.w);               \
                const float t1 = fmaf(m10, x0, m11 * x1);                     \
                const float e1 = fmaf(xv.z, d2.z, xv.w * d2.w);               \
                x0 += clipf(fmaf(t0, DT_C, e0), -MAXU, MAXU);                 \
                x1 += clipf(fmaf(t1, DT_C, e1), -MAXU, MAXU);                 \
            }                                                                 \
            out4[(BLK) * (UN / 2) + s / 2] = ov;                              \
        }                                                                     \
    }

    for (int blk = 0; blk < NBLK; blk += 2) {
        // prefetch stage blk+1 into B while computing stage blk from A
        {
            const float4* ip = in4 + (blk + 1) * (UN / 2);
            const float4* wp = w + (blk + 1) * UN;
#pragma unroll
            for (int i = 0; i < UN / 2; ++i) dyB[i] = ip[i];
#pragma unroll
            for (int i = 0; i < UN; ++i) xiB[i] = wp[i];
        }
        GRNN_STAGE(dyA, xiA, blk)
        // prefetch stage blk+2 into A while computing stage blk+1 from B
        if (blk + 2 < NBLK) {
            const float4* ip = in4 + (blk + 2) * (UN / 2);
            const float4* wp = w + (blk + 2) * UN;
#pragma unroll
            for (int i = 0; i < UN / 2; ++i) dyA[i] = ip[i];
#pragma unroll
            for (int i = 0; i < UN; ++i) xiA[i] = wp[i];
        }
        GRNN_STAGE(dyB, xiB, blk + 1)
    }
#undef GRNN_STAGE
}

// ---------------- fallback: round-2 monolithic kernel ----------------
__global__ __launch_bounds__(64) void grnn_mono(
    const float* __restrict__ inp, const float* __restrict__ Am,
    const float* __restrict__ Cm, const float* __restrict__ Dm,
    float* __restrict__ out, int B)
{
    const int b = blockIdx.x * blockDim.x + threadIdx.x;
    if (b >= B) return;
    const float a00 = Am[0], a01 = Am[1], a10 = Am[2], a11 = Am[3];
    const float c00 = Cm[0], c01 = Cm[1], c10 = Cm[2], c11 = Cm[3];
    const float d00 = Dm[0], d01 = Dm[1], d10 = Dm[2], d11 = Dm[3];
    float x0 = 1.0f, x1 = 0.0f;
    float p00 = 1.0f, p01 = 0.0f, p10 = 0.0f, p11 = 1.0f;
    const float2* __restrict__ in2 = reinterpret_cast<const float2*>(inp) + (size_t)b * T_LEN;
    float2* __restrict__ out2 = reinterpret_cast<float2*>(out) + (size_t)b * T_LEN;
#pragma unroll 4
    for (int t = 0; t < T_LEN; ++t) {
        float2 o;
        o.x = (c00 * x0 + c01 * x1) * DT_C;
        o.y = (c10 * x0 + c11 * x1) * DT_C;
        out2[t] = o;
        const float xi00 = p00 * c00 + p01 * c01 + d00;
        const float xi01 = p00 * c10 + p01 * c11 + d10;
        const float xi10 = p10 * c00 + p11 * c01 + d01;
        const float xi11 = p10 * c10 + p11 * c11 + d11;
        const float m00 = a00 - (xi00 * c00 + xi01 * c10);
        const float m01 = a01 - (xi00 * c01 + xi01 * c11);
        const float m10 = a10 - (xi10 * c00 + xi11 * c10);
        const float m11 = a11 - (xi10 * c01 + xi11 * c11);
        const float2 dy = in2[t];
        float dx0 = (m00 * x0 + m01 * x1) * DT_C + xi00 * dy.x + xi01 * dy.y;
        float dx1 = (m10 * x0 + m11 * x1) * DT_C + xi10 * dy.x + xi11 * dy.y;
        x0 += clipf(dx0, -MAXU, MAXU);
        x1 += clipf(dx1, -MAXU, MAXU);
        const float g00 = a00*p00 + a01*p10 + p00*a00 + p01*a01 + d00 - (xi00*xi00 + xi01*xi01);
        const float g01 = a00*p01 + a01*p11 + p00*a10 + p01*a11 + d01 - (xi00*xi10 + xi01*xi11);
        const float g10 = a10*p00 + a11*p10 + p10*a00 + p11*a01 + d10 - (xi10*xi00 + xi11*xi01);
        const float g11 = a10*p01 + a11*p11 + p10*a10 + p11*a11 + d11 - (xi10*xi10 + xi11*xi11);
        p00 = clipf(p00 + g00 * DT_C, -1.0f, 1.0f);
        p01 = clipf(p01 + g01 * DT_C, -1.0f, 1.0f);
        p10 = clipf(p10 + g10 * DT_C, -1.0f, 1.0f);
        p11 = clipf(p11 + g11 * DT_C, -1.0f, 1.0f);
    }
}

extern "C" void kernel_launch(void* const* d_in, const int* in_sizes, int n_in,
                              void* d_out, int out_size, void* d_ws, size_t ws_size,
                              hipStream_t stream) {
    const float* inp = (const float*)d_in[0];
    const float* Am  = (const float*)d_in[1];
    const float* Cm  = (const float*)d_in[2];
    const float* Dm  = (const float*)d_in[3];
    float* out = (float*)d_out;
    const int B = in_sizes[0] / (T_LEN * 2);  // 512

    if (ws_size >= WS_BYTES) {
        hipLaunchKernelGGL(grnn_producer, dim3(1), dim3(64), 0, stream,
                           Am, Cm, Dm, (float*)d_ws);
        hipLaunchKernelGGL(grnn_consumer, dim3(B), dim3(64), 0, stream,
                           inp, Am, Cm, (const float*)d_ws, out);
    } else {
        hipLaunchKernelGGL(grnn_mono, dim3((B + 63) / 64), dim3(64), 0, stream,
                           inp, Am, Cm, Dm, out, B);
    }
}

// Round 5
// 1175.060 us; speedup vs baseline: 1.7895x; 1.7895x over previous
//
#include <hip/hip_runtime.h>

// GRNN scan: B=512 sequences, T=8192 steps. Round 5.
// Producer (1 lane, runs once): cov/Xi recurrence is batch-independent.
//   Specialized path (runtime check C==I, D diagonal): P symmetric, ~36 inst/step.
//   Stores per step: {mdt00,mdt10,mdt01,mdt11},{xi00,xi10,xi01,xi11} (32 B).
// Consumer (8 blocks x 64 lanes, lane=batch): x recurrence, ~19 inst/step.
//   w-stream staged via LDS double-buffered 16 KB chunks (broadcast reads).
//   dy prefetched in 8 NAMED float4 registers (round-4 lesson: array buffers
//   got demoted to scratch, VGPR_Count=32 -> 433 cyc/step; named vars can't).

#define DT_C 1e-3f
#define MAXU 0.1f
#define T_LEN 8192
#define T4 (T_LEN / 2)            // float4 granules per batch = 4096
#define CHUNK 512                 // steps per LDS chunk
#define NCHUNK (T_LEN / CHUNK)    // 16
#define WS_BYTES (T_LEN * 8 * sizeof(float))   // 256 KB

__device__ __forceinline__ float clipf(float v, float lo, float hi) {
    return fminf(fmaxf(v, lo), hi);
}

// ---------------- producer: batch-invariant cov/Xi/Mdt recurrence ----------
__global__ __launch_bounds__(64) void grnn_producer(
    const float* __restrict__ Am, const float* __restrict__ Cm,
    const float* __restrict__ Dm, float* __restrict__ ws)
{
    if (threadIdx.x != 0) return;
    const float a00 = Am[0], a01 = Am[1], a10 = Am[2], a11 = Am[3];
    const float c00 = Cm[0], c01 = Cm[1], c10 = Cm[2], c11 = Cm[3];
    const float d00 = Dm[0], d01 = Dm[1], d10 = Dm[2], d11 = Dm[3];
    float4* __restrict__ w4 = reinterpret_cast<float4*>(ws);

    const bool special = (c00 == 1.0f) && (c01 == 0.0f) && (c10 == 0.0f) &&
                         (c11 == 1.0f) && (d01 == 0.0f) && (d10 == 0.0f);

    if (special) {
        // C = I, D = diag(d00, d11): P stays symmetric (p00, p01, p11).
        const float adt00 = a00 * DT_C, adt01 = a01 * DT_C;
        const float adt10 = a10 * DT_C, adt11 = a11 * DT_C;
        float p00 = 1.f, p01 = 0.f, p11 = 1.f;
#pragma unroll 4
        for (int t = 0; t < T_LEN; ++t) {
            const float xi00 = p00 + d00;
            const float xi01 = p01;              // == xi10
            const float xi11 = p11 + d11;
            float4 mv, xv;
            mv.x = fmaf(-DT_C, xi00, adt00);     // mdt00
            mv.y = fmaf(-DT_C, xi01, adt10);     // mdt10
            mv.z = fmaf(-DT_C, xi01, adt01);     // mdt01
            mv.w = fmaf(-DT_C, xi11, adt11);     // mdt11
            xv.x = xi00; xv.y = xi01; xv.z = xi01; xv.w = xi11;
            w4[2 * t]     = mv;
            w4[2 * t + 1] = xv;

            const float u00 = fmaf(a00, p00, a01 * p01);
            const float u01 = fmaf(a00, p01, a01 * p11);
            const float u10 = fmaf(a10, p00, a11 * p01);
            const float u11 = fmaf(a10, p01, a11 * p11);
            const float s  = xi01 * xi01;
            const float q00 = fmaf(xi00, xi00, s);
            const float q11 = fmaf(xi11, xi11, s);
            const float q01 = xi01 * (xi00 + xi11);
            const float g00 = fmaf(2.0f, u00, d00) - q00;
            const float g01 = (u01 + u10) - q01;
            const float g11 = fmaf(2.0f, u11, d11) - q11;
            p00 = __builtin_amdgcn_fmed3f(fmaf(g00, DT_C, p00), -1.f, 1.f);
            p01 = __builtin_amdgcn_fmed3f(fmaf(g01, DT_C, p01), -1.f, 1.f);
            p11 = __builtin_amdgcn_fmed3f(fmaf(g11, DT_C, p11), -1.f, 1.f);
        }
    } else {
        // generic path: full asymmetric P (matches the verified mono math)
        float p00 = 1.f, p01 = 0.f, p10 = 0.f, p11 = 1.f;
#pragma unroll 4
        for (int t = 0; t < T_LEN; ++t) {
            const float xi00 = p00 * c00 + p01 * c01 + d00;
            const float xi01 = p00 * c10 + p01 * c11 + d10;
            const float xi10 = p10 * c00 + p11 * c01 + d01;
            const float xi11 = p10 * c10 + p11 * c11 + d11;
            const float m00 = a00 - (xi00 * c00 + xi01 * c10);
            const float m01 = a01 - (xi00 * c01 + xi01 * c11);
            const float m10 = a10 - (xi10 * c00 + xi11 * c10);
            const float m11 = a11 - (xi10 * c01 + xi11 * c11);
            float4 mv, xv;
            mv.x = m00 * DT_C; mv.y = m10 * DT_C;
            mv.z = m01 * DT_C; mv.w = m11 * DT_C;
            xv.x = xi00; xv.y = xi10; xv.z = xi01; xv.w = xi11;
            w4[2 * t]     = mv;
            w4[2 * t + 1] = xv;
            const float g00 = a00*p00 + a01*p10 + p00*a00 + p01*a01 + d00 - (xi00*xi00 + xi01*xi01);
            const float g01 = a00*p01 + a01*p11 + p00*a10 + p01*a11 + d01 - (xi00*xi10 + xi01*xi11);
            const float g10 = a10*p00 + a11*p10 + p10*a00 + p11*a01 + d10 - (xi10*xi00 + xi11*xi01);
            const float g11 = a10*p01 + a11*p11 + p10*a10 + p11*a11 + d11 - (xi10*xi10 + xi11*xi11);
            p00 = clipf(p00 + g00 * DT_C, -1.f, 1.f);
            p01 = clipf(p01 + g01 * DT_C, -1.f, 1.f);
            p10 = clipf(p10 + g10 * DT_C, -1.f, 1.f);
            p11 = clipf(p11 + g11 * DT_C, -1.f, 1.f);
        }
    }
}

// ---------------- consumer: per-batch x recurrence ------------------------
__global__ __launch_bounds__(64, 1) void grnn_consumer(
    const float* __restrict__ inp, const float* __restrict__ Cm,
    const float* __restrict__ ws, float* __restrict__ out)
{
    __shared__ float4 wlds[2][CHUNK * 2];   // 2 x 16 KB

    const int lane = threadIdx.x;
    const int b = blockIdx.x * 64 + lane;

    const float cdt00 = Cm[0] * DT_C, cdt01 = Cm[1] * DT_C;
    const float cdt10 = Cm[2] * DT_C, cdt11 = Cm[3] * DT_C;

    const float4* __restrict__ in4 =
        reinterpret_cast<const float4*>(inp) + (size_t)b * T4;
    float4* __restrict__ out4 =
        reinterpret_cast<float4*>(out) + (size_t)b * T4;
    const float4* __restrict__ w4g = reinterpret_cast<const float4*>(ws);

    // stage chunk 0 (coalesced: 16 iters x 64 lanes x 16 B = 16 KB)
#pragma unroll
    for (int i = 0; i < 16; ++i)
        wlds[0][i * 64 + lane] = w4g[i * 64 + lane];

    float x0 = 1.f, x1 = 0.f;

    // dy prefetch pipeline: 8 NAMED float4 regs (2 steps each), 16 steps deep
    float4 d0 = in4[0], d1 = in4[1], d2 = in4[2], d3 = in4[3];
    float4 d4 = in4[4], d5 = in4[5], d6 = in4[6], d7 = in4[7];

#define GRAN(J)                                                               \
    {                                                                         \
        const float4 dyv = d##J;                                              \
        const float4 wa0 = wbuf[base + (J) * 4 + 0];                          \
        const float4 wb0 = wbuf[base + (J) * 4 + 1];                          \
        const float4 wa1 = wbuf[base + (J) * 4 + 2];                          \
        const float4 wb1 = wbuf[base + (J) * 4 + 3];                          \
        float4 ov;                                                            \
        ov.x = fmaf(cdt00, x0, cdt01 * x1);                                   \
        ov.y = fmaf(cdt10, x0, cdt11 * x1);                                   \
        {                                                                     \
            const float e0 = fmaf(wb0.x, dyv.x, wb0.z * dyv.y);               \
            const float e1 = fmaf(wb0.y, dyv.x, wb0.w * dyv.y);               \
            const float dx0 = fmaf(wa0.x, x0, fmaf(wa0.z, x1, e0));           \
            const float dx1 = fmaf(wa0.y, x0, fmaf(wa0.w, x1, e1));           \
            x0 += __builtin_amdgcn_fmed3f(dx0, -MAXU, MAXU);                  \
            x1 += __builtin_amdgcn_fmed3f(dx1, -MAXU, MAXU);                  \
        }                                                                     \
        ov.z = fmaf(cdt00, x0, cdt01 * x1);                                   \
        ov.w = fmaf(cdt10, x0, cdt11 * x1);                                   \
        {                                                                     \
            const float e0 = fmaf(wb1.x, dyv.z, wb1.z * dyv.w);               \
            const float e1 = fmaf(wb1.y, dyv.z, wb1.w * dyv.w);               \
            const float dx0 = fmaf(wa1.x, x0, fmaf(wa1.z, x1, e0));           \
            const float dx1 = fmaf(wa1.y, x0, fmaf(wa1.w, x1, e1));           \
            x0 += __builtin_amdgcn_fmed3f(dx0, -MAXU, MAXU);                  \
            x1 += __builtin_amdgcn_fmed3f(dx1, -MAXU, MAXU);                  \
        }                                                                     \
        const int og = ogbase + (J);                                          \
        out4[og] = ov;                                                        \
        d##J = in4[min(og + 8, T4 - 1)];                                      \
    }

    for (int chunk = 0; chunk < NCHUNK; ++chunk) {
        // stage next chunk into the other LDS buffer while computing this one
        if (chunk + 1 < NCHUNK) {
            float4* dst = wlds[(chunk + 1) & 1];
            const float4* src = w4g + (size_t)(chunk + 1) * (CHUNK * 2);
#pragma unroll
            for (int i = 0; i < 16; ++i)
                dst[i * 64 + lane] = src[i * 64 + lane];
        }
        const float4* wbuf = wlds[chunk & 1];
        for (int iter = 0; iter < CHUNK / 16; ++iter) {   // 32 iters x 8 granules
            const int base = iter * 32;                   // float4 idx in chunk
            const int ogbase = chunk * (CHUNK / 2) + iter * 8;
            GRAN(0) GRAN(1) GRAN(2) GRAN(3)
            GRAN(4) GRAN(5) GRAN(6) GRAN(7)
        }
    }
#undef GRAN
}

// ---------------- fallback: verified monolithic kernel --------------------
__global__ __launch_bounds__(64) void grnn_mono(
    const float* __restrict__ inp, const float* __restrict__ Am,
    const float* __restrict__ Cm, const float* __restrict__ Dm,
    float* __restrict__ out, int B)
{
    const int b = blockIdx.x * blockDim.x + threadIdx.x;
    if (b >= B) return;
    const float a00 = Am[0], a01 = Am[1], a10 = Am[2], a11 = Am[3];
    const float c00 = Cm[0], c01 = Cm[1], c10 = Cm[2], c11 = Cm[3];
    const float d00 = Dm[0], d01 = Dm[1], d10 = Dm[2], d11 = Dm[3];
    float x0 = 1.0f, x1 = 0.0f;
    float p00 = 1.0f, p01 = 0.0f, p10 = 0.0f, p11 = 1.0f;
    const float2* __restrict__ in2 = reinterpret_cast<const float2*>(inp) + (size_t)b * T_LEN;
    float2* __restrict__ out2 = reinterpret_cast<float2*>(out) + (size_t)b * T_LEN;
#pragma unroll 4
    for (int t = 0; t < T_LEN; ++t) {
        float2 o;
        o.x = (c00 * x0 + c01 * x1) * DT_C;
        o.y = (c10 * x0 + c11 * x1) * DT_C;
        out2[t] = o;
        const float xi00 = p00 * c00 + p01 * c01 + d00;
        const float xi01 = p00 * c10 + p01 * c11 + d10;
        const float xi10 = p10 * c00 + p11 * c01 + d01;
        const float xi11 = p10 * c10 + p11 * c11 + d11;
        const float m00 = a00 - (xi00 * c00 + xi01 * c10);
        const float m01 = a01 - (xi00 * c01 + xi01 * c11);
        const float m10 = a10 - (xi10 * c00 + xi11 * c10);
        const float m11 = a11 - (xi10 * c01 + xi11 * c11);
        const float2 dy = in2[t];
        float dx0 = (m00 * x0 + m01 * x1) * DT_C + xi00 * dy.x + xi01 * dy.y;
        float dx1 = (m10 * x0 + m11 * x1) * DT_C + xi10 * dy.x + xi11 * dy.y;
        x0 += clipf(dx0, -MAXU, MAXU);
        x1 += clipf(dx1, -MAXU, MAXU);
        const float g00 = a00*p00 + a01*p10 + p00*a00 + p01*a01 + d00 - (xi00*xi00 + xi01*xi01);
        const float g01 = a00*p01 + a01*p11 + p00*a10 + p01*a11 + d01 - (xi00*xi10 + xi01*xi11);
        const float g10 = a10*p00 + a11*p10 + p10*a00 + p11*a01 + d10 - (xi10*xi00 + xi11*xi01);
        const float g11 = a10*p01 + a11*p11 + p10*a10 + p11*a11 + d11 - (xi10*xi10 + xi11*xi11);
        p00 = clipf(p00 + g00 * DT_C, -1.0f, 1.0f);
        p01 = clipf(p01 + g01 * DT_C, -1.0f, 1.0f);
        p10 = clipf(p10 + g10 * DT_C, -1.0f, 1.0f);
        p11 = clipf(p11 + g11 * DT_C, -1.0f, 1.0f);
    }
}

extern "C" void kernel_launch(void* const* d_in, const int* in_sizes, int n_in,
                              void* d_out, int out_size, void* d_ws, size_t ws_size,
                              hipStream_t stream) {
    const float* inp = (const float*)d_in[0];
    const float* Am  = (const float*)d_in[1];
    const float* Cm  = (const float*)d_in[2];
    const float* Dm  = (const float*)d_in[3];
    float* out = (float*)d_out;
    const int B = in_sizes[0] / (T_LEN * 2);  // 512

    if (ws_size >= WS_BYTES && (B % 64) == 0) {
        hipLaunchKernelGGL(grnn_producer, dim3(1), dim3(64), 0, stream,
                           Am, Cm, Dm, (float*)d_ws);
        hipLaunchKernelGGL(grnn_consumer, dim3(B / 64), dim3(64), 0, stream,
                           inp, Cm, (const float*)d_ws, out);
    } else {
        hipLaunchKernelGGL(grnn_mono, dim3((B + 63) / 64), dim3(64), 0, stream,
                           inp, Am, Cm, Dm, out, B);
    }
}